// Round 11
// baseline (1432.246 us; speedup 1.0000x reference)
//
#include <hip/hip_runtime.h>

#define NN 100000
#define NE 1600000
#define NG 512

#define BSH 9                         // bucket = dst >> 9 (512 nodes/bucket)
#define NB 196                        // ceil(NN / 512)
#define EPB 8192                      // edges per block in phase A
#define NAB ((NE + EPB - 1) / EPB)    // 196 phase-A blocks
#define CAP 9216                      // LDS staging capacity in kB_build

// ---------- embedding lookup + pre-linear + relu: x1[N,32] ----------
__global__ __launch_bounds__(256) void k_embed(
    const int* __restrict__ nf, const float* __restrict__ semb,
    const float* __restrict__ cemb, const float* __restrict__ pw,
    const float* __restrict__ pb, float* __restrict__ x1)
{
  int gid = blockIdx.x * 256 + threadIdx.x;
  bool valid = gid < NN;
  int i = valid ? gid : NN - 1;
  int sf = nf[2 * i], cf = nf[2 * i + 1];
  float x0[16];
#pragma unroll
  for (int k = 0; k < 8; ++k) x0[k] = semb[sf * 8 + k];
#pragma unroll
  for (int k = 0; k < 8; ++k) x0[8 + k] = cemb[cf * 8 + k];
  float acc[32];
#pragma unroll
  for (int j = 0; j < 32; ++j) acc[j] = pb[j];
#pragma unroll
  for (int k = 0; k < 16; ++k) {
    float xv = x0[k];
#pragma unroll
    for (int j = 0; j < 32; ++j) acc[j] += xv * pw[k * 32 + j];
  }
  if (valid) {
    float4* o = (float4*)(x1 + (size_t)i * 32);
#pragma unroll
    for (int j4 = 0; j4 < 8; ++j4) {
      float4 v;
      v.x = fmaxf(acc[4 * j4 + 0], 0.f);
      v.y = fmaxf(acc[4 * j4 + 1], 0.f);
      v.z = fmaxf(acc[4 * j4 + 2], 0.f);
      v.w = fmaxf(acc[4 * j4 + 3], 0.f);
      o[j4] = v;
    }
  }
}

// ---------- CSR build via bucketed counting sort ----------

__global__ __launch_bounds__(256) void kA_count(
    const int* __restrict__ ei, int* __restrict__ bkt_cnt)
{
  __shared__ int lh[NB];
  for (int b = threadIdx.x; b < NB; b += 256) lh[b] = 0;
  __syncthreads();
  int base = blockIdx.x * EPB;
#pragma unroll
  for (int i = 0; i < EPB / 256; ++i) {
    int e = base + i * 256 + threadIdx.x;
    if (e < NE) atomicAdd(&lh[ei[NE + e] >> BSH], 1);
  }
  __syncthreads();
  for (int b = threadIdx.x; b < NB; b += 256)
    if (lh[b]) atomicAdd(&bkt_cnt[b], lh[b]);
}

__global__ __launch_bounds__(256) void kA_scan(
    const int* __restrict__ bkt_cnt, int* __restrict__ bkt_base,
    int* __restrict__ bkt_cur)
{
  __shared__ int sm[2][256];
  int t = threadIdx.x;
  int v = (t < NB) ? bkt_cnt[t] : 0;
  sm[0][t] = v;
  __syncthreads();
  int cur = 0;
#pragma unroll
  for (int off = 1; off < 256; off <<= 1) {
    int add = (t >= off) ? sm[cur][t - off] : 0;
    sm[cur ^ 1][t] = sm[cur][t] + add;
    __syncthreads();
    cur ^= 1;
  }
  if (t < NB) {
    int ex = sm[cur][t] - v;
    bkt_base[t] = ex;
    bkt_cur[t] = ex;
  }
  if (t == 0) bkt_base[NB] = NE;
}

// pack: src(0-16) | type(17-18) | dst&511 (19-27)
__global__ __launch_bounds__(256) void kA_scatter(
    const int* __restrict__ ei, const int* __restrict__ et,
    int* __restrict__ bkt_cur, int* __restrict__ binned)
{
  __shared__ int packA[EPB];
  __shared__ unsigned char bktA[EPB];
  __shared__ int lh[NB], grun[NB], lcur[NB];
  for (int b = threadIdx.x; b < NB; b += 256) { lh[b] = 0; lcur[b] = 0; }
  __syncthreads();
  int base = blockIdx.x * EPB;
#pragma unroll
  for (int i = 0; i < EPB / 256; ++i) {
    int p = i * 256 + threadIdx.x;
    int e = base + p;
    if (e < NE) {
      int src = ei[e], dst = ei[NE + e], ty = et[e];
      int b = dst >> BSH;
      packA[p] = src | (ty << 17) | ((dst & 511) << 19);
      bktA[p] = (unsigned char)b;
      atomicAdd(&lh[b], 1);
    } else {
      bktA[p] = 255;
    }
  }
  __syncthreads();
  for (int b = threadIdx.x; b < NB; b += 256)
    grun[b] = lh[b] ? atomicAdd(&bkt_cur[b], lh[b]) : 0;
  __syncthreads();
#pragma unroll
  for (int i = 0; i < EPB / 256; ++i) {
    int p = i * 256 + threadIdx.x;
    int b = bktA[p];
    if (b != 255) {
      int off = atomicAdd(&lcur[b], 1);
      binned[grun[b] + off] = packA[p];
    }
  }
}

// Phase B: one workgroup per bucket; key = dst_local*3 + type -> per-node
// edge list sorted by relation; rs3[d*3+r] run boundaries; ep stores src.
__global__ __launch_bounds__(512) void kB_build(
    const int* __restrict__ bkt_base, const int* __restrict__ binned,
    int* __restrict__ rs3, int* __restrict__ ep)
{
  __shared__ int stage[CAP];
  __shared__ int ldeg3[1536], lrs3[1536], lcur3[1536];
  __shared__ int sm[2][512];
  int b = blockIdx.x;
  int t = threadIdx.x;
  int p0 = bkt_base[b], p1 = bkt_base[b + 1];
  int cnt = p1 - p0;
  int nodes0 = b << BSH;
  int nnodes = NN - nodes0 < 512 ? NN - nodes0 : 512;
  ldeg3[t] = 0; ldeg3[t + 512] = 0; ldeg3[t + 1024] = 0;
  lcur3[t] = 0; lcur3[t + 512] = 0; lcur3[t + 1024] = 0;
  __syncthreads();
  for (int p = t; p < cnt; p += 512) {
    int pk = binned[p0 + p];
    if (p < CAP) stage[p] = pk;
    int key = ((pk >> 19) & 511) * 3 + ((pk >> 17) & 3);
    atomicAdd(&ldeg3[key], 1);
  }
  __syncthreads();
  int s0 = ldeg3[3 * t], s1 = ldeg3[3 * t + 1], s2 = ldeg3[3 * t + 2];
  int tot = s0 + s1 + s2;
  sm[0][t] = tot;
  __syncthreads();
  int cur = 0;
#pragma unroll
  for (int off = 1; off < 512; off <<= 1) {
    int add = (t >= off) ? sm[cur][t - off] : 0;
    sm[cur ^ 1][t] = sm[cur][t] + add;
    __syncthreads();
    cur ^= 1;
  }
  int ex = sm[cur][t] - tot;  // exclusive
  int r0 = p0 + ex, r1 = r0 + s0, r2 = r1 + s1;
  lrs3[3 * t] = r0;
  lrs3[3 * t + 1] = r1;
  lrs3[3 * t + 2] = r2;
  if (t < nnodes) {
    size_t base3 = (size_t)(nodes0 + t) * 3;
    rs3[base3 + 0] = r0;
    rs3[base3 + 1] = r1;
    rs3[base3 + 2] = r2;
  }
  if (b == NB - 1 && t == 0) rs3[(size_t)NN * 3] = NE;
  __syncthreads();
  for (int p = t; p < cnt; p += 512) {
    int pk = (p < CAP) ? stage[p] : binned[p0 + p];
    int key = ((pk >> 19) & 511) * 3 + ((pk >> 17) & 3);
    int off = atomicAdd(&lcur3[key], 1);
    ep[lrs3[key] + off] = pk & 0x1FFFF;  // src only
  }
}

// ---------- per-relation mean aggregation (R10 proven: float4 lane-group
// gather over the unified type-sorted run, position-mask demux) ----------
template <int IN>
__global__ __launch_bounds__(256) void k_agg(
    const float* __restrict__ x, const int* __restrict__ rs3,
    const int* __restrict__ ep, float* __restrict__ h)
{
  constexpr int LPE = IN / 4;            // lanes per edge-row (16 or 8)
  constexpr int DPW = (IN == 32) ? 2 : 1;
  constexpr int SW = 64 / DPW;           // lanes per dst (64 or 32)
  constexpr int EPI = SW / LPE;          // 4 edges per iteration
  int tid = threadIdx.x;
  int wid = (blockIdx.x * 256 + tid) >> 6;
  int lane = tid & 63;
  int sub = lane / SW;
  int sl = lane % SW;
  int k4 = sl % LPE;                     // float4 column within row
  int es = sl / LPE;                     // edge slot 0..3
  int d = wid * DPW + sub;
  if (d >= NN) return;
  int q0 = rs3[3 * d + 0];
  int q1 = rs3[3 * d + 1];
  int q2 = rs3[3 * d + 2];
  int q3 = rs3[3 * d + 3];
  float4 a0 = make_float4(0.f, 0.f, 0.f, 0.f);
  float4 a1 = make_float4(0.f, 0.f, 0.f, 0.f);
  float4 a2 = make_float4(0.f, 0.f, 0.f, 0.f);
#pragma unroll 2
  for (int p = q0; p < q3; p += EPI) {
    int idx = p + es;
    bool val = idx < q3;
    int e = ep[val ? idx : q3 - 1];
    float4 v = *(const float4*)(x + (size_t)e * IN + k4 * 4);
    float m0 = (val && idx < q1) ? 1.f : 0.f;
    float m1 = (val && idx >= q1 && idx < q2) ? 1.f : 0.f;
    float m2 = (val && idx >= q2) ? 1.f : 0.f;
    a0.x = fmaf(m0, v.x, a0.x); a0.y = fmaf(m0, v.y, a0.y);
    a0.z = fmaf(m0, v.z, a0.z); a0.w = fmaf(m0, v.w, a0.w);
    a1.x = fmaf(m1, v.x, a1.x); a1.y = fmaf(m1, v.y, a1.y);
    a1.z = fmaf(m1, v.z, a1.z); a1.w = fmaf(m1, v.w, a1.w);
    a2.x = fmaf(m2, v.x, a2.x); a2.y = fmaf(m2, v.y, a2.y);
    a2.z = fmaf(m2, v.z, a2.z); a2.w = fmaf(m2, v.w, a2.w);
  }
#pragma unroll
  for (int off = LPE; off < SW; off <<= 1) {
    a0.x += __shfl_xor(a0.x, off, 64); a0.y += __shfl_xor(a0.y, off, 64);
    a0.z += __shfl_xor(a0.z, off, 64); a0.w += __shfl_xor(a0.w, off, 64);
    a1.x += __shfl_xor(a1.x, off, 64); a1.y += __shfl_xor(a1.y, off, 64);
    a1.z += __shfl_xor(a1.z, off, 64); a1.w += __shfl_xor(a1.w, off, 64);
    a2.x += __shfl_xor(a2.x, off, 64); a2.y += __shfl_xor(a2.y, off, 64);
    a2.z += __shfl_xor(a2.z, off, 64); a2.w += __shfl_xor(a2.w, off, 64);
  }
  if (es == 0) {
    float* hd = h + (size_t)d * 3 * IN;
    float c0 = (float)(q1 - q0 > 0 ? q1 - q0 : 1);
    float c1 = (float)(q2 - q1 > 0 ? q2 - q1 : 1);
    float c2 = (float)(q3 - q2 > 0 ? q3 - q2 : 1);
    float4 o;
    o.x = a0.x / c0; o.y = a0.y / c0; o.z = a0.z / c0; o.w = a0.w / c0;
    *(float4*)(hd + 0 * IN + k4 * 4) = o;
    o.x = a1.x / c1; o.y = a1.y / c1; o.z = a1.z / c1; o.w = a1.w / c1;
    *(float4*)(hd + 1 * IN + k4 * 4) = o;
    o.x = a2.x / c2; o.y = a2.y / c2; o.z = a2.z / c2; o.w = a2.w / c2;
    *(float4*)(hd + 2 * IN + k4 * 4) = o;
  }
}

// ---------- dense: y[d] = relu(x[d]@root + bias + sum_r h[d][r]@rel_r) ----------
// Persistent, register-double-pumped. R10's k_mat staged 64KB, then computed
// 3.4us with memory idle (1 TB/s realized, VALU 34%): duty-cycle bound.
// Here each block grid-strides over tiles: issue(t+1)'s global loads go to
// REGISTERS before compute(t) (HBM latency hides under ~4k cyc of FMA),
// then barrier -> ds_write regs->LDS -> barrier. Memory + VALU both stay
// busy. All 4 streams live in LDS at once: smem[4*IN][64] = 64KB (IN=64,
// 2 blocks/CU) / 32KB (IN=32, 4 blocks/CU = 32 waves).
// No pad (4*IN*65 would exceed 64KB): XOR swizzle instead -- element
// (stream row rl, node c) stored at column c ^ (rl & ~3). Write instrs:
// 64 lanes hit 64 distinct columns (2/bank, free). Read per 4-row group:
// col = n ^ kq computed once, 4 ds_reads via offset: immediates (2 extra
// VALU per 4 k). Weight reads stay wave-uniform s_loads (j0 readfirstlane).
template <int IN>
__global__ __launch_bounds__(512) void k_mat(
    const float* __restrict__ x, const float* __restrict__ h,
    const float* __restrict__ root, const float* __restrict__ rel,
    const float* __restrict__ bias, float* __restrict__ y)
{
  constexpr int F4 = IN / 4;            // float4 per row
  constexpr int SPT = 64 * F4;          // float4 per stream-tile
  constexpr int NPF = (4 * SPT) / 512;  // staged float4 per thread (8 / 4)
  __shared__ float smem[4 * IN * 64];

  const int tid = threadIdx.x;
  const int n = tid & 63;
  const int j0 = __builtin_amdgcn_readfirstlane((tid >> 6) * 8);
  const int ntiles = (NN + 63) / 64;

  float4 p[NPF];

  auto issue = [&](int tl) {
    int node0 = tl * 64;
#pragma unroll
    for (int u = 0; u < NPF; ++u) {
      int idx = u * 512 + tid;
      int s = idx / SPT;
      int rem = idx - s * SPT;
      int nn = rem / F4;
      int c4 = rem - nn * F4;
      int node = node0 + nn;
      float4 v = make_float4(0.f, 0.f, 0.f, 0.f);
      if (node < NN) {
        const float* src = (s == 0) ? x + (size_t)node * IN
                                    : h + ((size_t)node * 3 + (s - 1)) * IN;
        v = *(const float4*)(src + c4 * 4);
      }
      p[u] = v;
    }
  };

  auto commit = [&]() {
#pragma unroll
    for (int u = 0; u < NPF; ++u) {
      int idx = u * 512 + tid;
      int s = idx / SPT;
      int rem = idx - s * SPT;
      int nn = rem / F4;
      int c4 = rem - nn * F4;
      int base = (s * IN + 4 * c4) * 64 + (nn ^ (4 * c4));
      smem[base + 0 * 64] = p[u].x;
      smem[base + 1 * 64] = p[u].y;
      smem[base + 2 * 64] = p[u].z;
      smem[base + 3 * 64] = p[u].w;
    }
  };

  float acc[8];
  auto mm = [&](const float* __restrict__ W, int row0) {
#pragma unroll
    for (int kq = 0; kq < IN; kq += 4) {
      const float* b = &smem[(row0 + kq) * 64 + (n ^ kq)];
#pragma unroll
      for (int i = 0; i < 4; ++i) {
        float sk = b[i * 64];
        const float* w = W + (size_t)(kq + i) * 64 + j0;
#pragma unroll
        for (int j = 0; j < 8; ++j) acc[j] = fmaf(sk, w[j], acc[j]);
      }
    }
  };

  int tile = blockIdx.x;
  if (tile >= ntiles) return;
  issue(tile);
  commit();
  __syncthreads();

  for (;;) {
    int nxt = tile + gridDim.x;
    bool more = nxt < ntiles;
    if (more) issue(nxt);  // in flight under the mm's below

#pragma unroll
    for (int j = 0; j < 8; ++j) acc[j] = bias[j0 + j];
    mm(root, 0);
    mm(rel, IN);
    mm(rel + (size_t)IN * 64, 2 * IN);
    mm(rel + (size_t)2 * IN * 64, 3 * IN);

    int node = tile * 64 + n;
    if (node < NN) {
      float4* o = (float4*)(y + (size_t)node * 64 + j0);
      float4 v;
      v.x = fmaxf(acc[0], 0.f); v.y = fmaxf(acc[1], 0.f);
      v.z = fmaxf(acc[2], 0.f); v.w = fmaxf(acc[3], 0.f);
      o[0] = v;
      v.x = fmaxf(acc[4], 0.f); v.y = fmaxf(acc[5], 0.f);
      v.z = fmaxf(acc[6], 0.f); v.w = fmaxf(acc[7], 0.f);
      o[1] = v;
    }
    if (!more) break;
    __syncthreads();   // all waves done reading smem
    commit();          // waits vmcnt for p, then ds_write
    __syncthreads();
    tile = nxt;
  }
}

// ---------- mean pool over sorted batch ids (run-length reduce, then atomic) ----------
__global__ __launch_bounds__(256) void k_pool(
    const float* __restrict__ x3, const int* __restrict__ batch,
    float* __restrict__ pooled, float* __restrict__ gcnt)
{
  int gwave = (blockIdx.x * 256 + threadIdx.x) >> 6;
  int lane = threadIdx.x & 63;
  int n0 = gwave * 64;
  if (n0 >= NN) return;
  int n1 = n0 + 64 < NN ? n0 + 64 : NN;
  int gcur = batch[n0];
  float acc = 0.f;
  int run = 0;
  for (int n = n0; n < n1; ++n) {
    int g = batch[n];
    if (g != gcur) {
      atomicAdd(&pooled[gcur * 64 + lane], acc);
      if (lane == 0) atomicAdd(&gcnt[gcur], (float)run);
      acc = 0.f; run = 0; gcur = g;
    }
    acc += x3[(size_t)n * 64 + lane];
    ++run;
  }
  atomicAdd(&pooled[gcur * 64 + lane], acc);
  if (lane == 0) atomicAdd(&gcnt[gcur], (float)run);
}

// ---------- classifier ----------
__global__ __launch_bounds__(256) void k_cls(
    const float* __restrict__ pooled, const float* __restrict__ gcnt,
    const float* __restrict__ cw, const float* __restrict__ cb, float* __restrict__ out)
{
  int t = blockIdx.x * 256 + threadIdx.x;
  if (t >= NG * 10) return;
  int g = t / 10, c = t % 10;
  float cf = fmaxf(gcnt[g], 1.f);
  float acc = cb[c];
#pragma unroll 8
  for (int k = 0; k < 64; ++k)
    acc += (pooled[g * 64 + k] / cf) * cw[k * 10 + c];
  out[t] = acc;
}

extern "C" void kernel_launch(void* const* d_in, const int* in_sizes, int n_in,
                              void* d_out, int out_size, void* d_ws, size_t ws_size,
                              hipStream_t stream)
{
  const int* nf = (const int*)d_in[0];
  const int* ei = (const int*)d_in[1];
  const int* et = (const int*)d_in[2];
  const int* batch = (const int*)d_in[3];
  const float* semb = (const float*)d_in[4];
  const float* cemb = (const float*)d_in[5];
  const float* pw = (const float*)d_in[6];
  const float* pb = (const float*)d_in[7];
  const float* root1 = (const float*)d_in[8];
  const float* rel1 = (const float*)d_in[9];
  const float* bias1 = (const float*)d_in[10];
  const float* root2 = (const float*)d_in[11];
  const float* rel2 = (const float*)d_in[12];
  const float* bias2 = (const float*)d_in[13];
  const float* cw = (const float*)d_in[14];
  const float* cb = (const float*)d_in[15];
  float* out = (float*)d_out;

  char* ws = (char*)d_ws;
  size_t off = 0;
  auto alloc = [&](size_t bytes) {
    char* p = ws + off;
    off += (bytes + 255) & ~(size_t)255;
    return p;
  };
  int* bkt_cnt = (int*)alloc((size_t)NB * 4);
  int* bkt_base = (int*)alloc((size_t)(NB + 1) * 4);
  int* bkt_cur = (int*)alloc((size_t)NB * 4);
  int* rs3 = (int*)alloc(((size_t)NN * 3 + 1) * 4);  // per-(node,type) run starts
  int* ep = (int*)alloc((size_t)NE * 4 + 256);       // src, type-sorted CSR order
  float* xA = (float*)alloc((size_t)NN * 64 * 4);    // x2
  float* xB = (float*)alloc((size_t)NN * 64 * 4);    // x1 ([N,32]) then x3
  float* h = (float*)alloc((size_t)3 * NN * 64 * 4); // h[d][r][IN]
  float* pooled = (float*)alloc((size_t)NG * 64 * 4);
  float* gcnt = (float*)alloc((size_t)NG * 4);
  int* binned = (int*)h;  // phase-A output; consumed by kB_build before k_agg writes h
  (void)ws_size; (void)in_sizes; (void)n_in; (void)out_size;

  hipMemsetAsync(bkt_cnt, 0, (size_t)NB * 4, stream);
  k_embed<<<(NN + 255) / 256, 256, 0, stream>>>(nf, semb, cemb, pw, pb, xB);

  // CSR build: bucketed counting sort, type-sorted within node
  kA_count<<<NAB, 256, 0, stream>>>(ei, bkt_cnt);
  kA_scan<<<1, 256, 0, stream>>>(bkt_cnt, bkt_base, bkt_cur);
  kA_scatter<<<NAB, 256, 0, stream>>>(ei, et, bkt_cur, binned);
  kB_build<<<NB, 512, 0, stream>>>(bkt_base, binned, rs3, ep);

  // persistent k_mat grids: 2 blocks/CU (64KB LDS) for IN=64, 4/CU for IN=32
  int matgrid64 = 512;
  int matgrid32 = 1024;

  // layer 1: x1[N,32] (xB) -> h -> x2[N,64] (xA)
  k_agg<32><<<(NN / 2 + 3) / 4 + 1, 256, 0, stream>>>(xB, rs3, ep, h);
  k_mat<32><<<matgrid32, 512, 0, stream>>>(xB, h, root1, rel1, bias1, xA);
  // layer 2: x2 (xA) -> h -> x3 (xB)
  k_agg<64><<<(NN + 3) / 4, 256, 0, stream>>>(xA, rs3, ep, h);
  k_mat<64><<<matgrid64, 512, 0, stream>>>(xA, h, root2, rel2, bias2, xB);

  hipMemsetAsync(pooled, 0, (size_t)NG * 64 * 4, stream);
  hipMemsetAsync(gcnt, 0, (size_t)NG * 4, stream);
  int nwaves = (NN + 63) / 64;
  k_pool<<<(nwaves + 3) / 4, 256, 0, stream>>>(xB, batch, pooled, gcnt);
  k_cls<<<(NG * 10 + 255) / 256, 256, 0, stream>>>(pooled, gcnt, cw, cb, out);
}

// Round 12
// 294.294 us; speedup vs baseline: 4.8667x; 4.8667x over previous
//
#include <hip/hip_runtime.h>

#define NN 100000
#define NE 1600000
#define NG 512

#define BSH 9                         // bucket = dst >> 9 (512 nodes/bucket)
#define NB 196                        // ceil(NN / 512)
#define EPB 8192                      // edges per block in phase A
#define NAB ((NE + EPB - 1) / EPB)    // 196 phase-A blocks
#define CAP 9216                      // LDS staging capacity in kB_build

// ---------- embedding lookup + pre-linear + relu: x1[N,32] ----------
__global__ __launch_bounds__(256) void k_embed(
    const int* __restrict__ nf, const float* __restrict__ semb,
    const float* __restrict__ cemb, const float* __restrict__ pw,
    const float* __restrict__ pb, float* __restrict__ x1)
{
  int gid = blockIdx.x * 256 + threadIdx.x;
  bool valid = gid < NN;
  int i = valid ? gid : NN - 1;
  int sf = nf[2 * i], cf = nf[2 * i + 1];
  float x0[16];
#pragma unroll
  for (int k = 0; k < 8; ++k) x0[k] = semb[sf * 8 + k];
#pragma unroll
  for (int k = 0; k < 8; ++k) x0[8 + k] = cemb[cf * 8 + k];
  float acc[32];
#pragma unroll
  for (int j = 0; j < 32; ++j) acc[j] = pb[j];
#pragma unroll
  for (int k = 0; k < 16; ++k) {
    float xv = x0[k];
#pragma unroll
    for (int j = 0; j < 32; ++j) acc[j] += xv * pw[k * 32 + j];
  }
  if (valid) {
    float4* o = (float4*)(x1 + (size_t)i * 32);
#pragma unroll
    for (int j4 = 0; j4 < 8; ++j4) {
      float4 v;
      v.x = fmaxf(acc[4 * j4 + 0], 0.f);
      v.y = fmaxf(acc[4 * j4 + 1], 0.f);
      v.z = fmaxf(acc[4 * j4 + 2], 0.f);
      v.w = fmaxf(acc[4 * j4 + 3], 0.f);
      o[j4] = v;
    }
  }
}

// ---------- CSR build via bucketed counting sort ----------

__global__ __launch_bounds__(256) void kA_count(
    const int* __restrict__ ei, int* __restrict__ bkt_cnt)
{
  __shared__ int lh[NB];
  for (int b = threadIdx.x; b < NB; b += 256) lh[b] = 0;
  __syncthreads();
  int base = blockIdx.x * EPB;
#pragma unroll
  for (int i = 0; i < EPB / 256; ++i) {
    int e = base + i * 256 + threadIdx.x;
    if (e < NE) atomicAdd(&lh[ei[NE + e] >> BSH], 1);
  }
  __syncthreads();
  for (int b = threadIdx.x; b < NB; b += 256)
    if (lh[b]) atomicAdd(&bkt_cnt[b], lh[b]);
}

__global__ __launch_bounds__(256) void kA_scan(
    const int* __restrict__ bkt_cnt, int* __restrict__ bkt_base,
    int* __restrict__ bkt_cur)
{
  __shared__ int sm[2][256];
  int t = threadIdx.x;
  int v = (t < NB) ? bkt_cnt[t] : 0;
  sm[0][t] = v;
  __syncthreads();
  int cur = 0;
#pragma unroll
  for (int off = 1; off < 256; off <<= 1) {
    int add = (t >= off) ? sm[cur][t - off] : 0;
    sm[cur ^ 1][t] = sm[cur][t] + add;
    __syncthreads();
    cur ^= 1;
  }
  if (t < NB) {
    int ex = sm[cur][t] - v;
    bkt_base[t] = ex;
    bkt_cur[t] = ex;
  }
  if (t == 0) bkt_base[NB] = NE;
}

// pack: src(0-16) | type(17-18) | dst&511 (19-27)
__global__ __launch_bounds__(256) void kA_scatter(
    const int* __restrict__ ei, const int* __restrict__ et,
    int* __restrict__ bkt_cur, int* __restrict__ binned)
{
  __shared__ int packA[EPB];
  __shared__ unsigned char bktA[EPB];
  __shared__ int lh[NB], grun[NB], lcur[NB];
  for (int b = threadIdx.x; b < NB; b += 256) { lh[b] = 0; lcur[b] = 0; }
  __syncthreads();
  int base = blockIdx.x * EPB;
#pragma unroll
  for (int i = 0; i < EPB / 256; ++i) {
    int p = i * 256 + threadIdx.x;
    int e = base + p;
    if (e < NE) {
      int src = ei[e], dst = ei[NE + e], ty = et[e];
      int b = dst >> BSH;
      packA[p] = src | (ty << 17) | ((dst & 511) << 19);
      bktA[p] = (unsigned char)b;
      atomicAdd(&lh[b], 1);
    } else {
      bktA[p] = 255;
    }
  }
  __syncthreads();
  for (int b = threadIdx.x; b < NB; b += 256)
    grun[b] = lh[b] ? atomicAdd(&bkt_cur[b], lh[b]) : 0;
  __syncthreads();
#pragma unroll
  for (int i = 0; i < EPB / 256; ++i) {
    int p = i * 256 + threadIdx.x;
    int b = bktA[p];
    if (b != 255) {
      int off = atomicAdd(&lcur[b], 1);
      binned[grun[b] + off] = packA[p];
    }
  }
}

// Phase B: one workgroup per bucket; key = dst_local*3 + type -> per-node
// edge list sorted by relation; rs3[d*3+r] run boundaries; ep stores src.
__global__ __launch_bounds__(512) void kB_build(
    const int* __restrict__ bkt_base, const int* __restrict__ binned,
    int* __restrict__ rs3, int* __restrict__ ep)
{
  __shared__ int stage[CAP];
  __shared__ int ldeg3[1536], lrs3[1536], lcur3[1536];
  __shared__ int sm[2][512];
  int b = blockIdx.x;
  int t = threadIdx.x;
  int p0 = bkt_base[b], p1 = bkt_base[b + 1];
  int cnt = p1 - p0;
  int nodes0 = b << BSH;
  int nnodes = NN - nodes0 < 512 ? NN - nodes0 : 512;
  ldeg3[t] = 0; ldeg3[t + 512] = 0; ldeg3[t + 1024] = 0;
  lcur3[t] = 0; lcur3[t + 512] = 0; lcur3[t + 1024] = 0;
  __syncthreads();
  for (int p = t; p < cnt; p += 512) {
    int pk = binned[p0 + p];
    if (p < CAP) stage[p] = pk;
    int key = ((pk >> 19) & 511) * 3 + ((pk >> 17) & 3);
    atomicAdd(&ldeg3[key], 1);
  }
  __syncthreads();
  int s0 = ldeg3[3 * t], s1 = ldeg3[3 * t + 1], s2 = ldeg3[3 * t + 2];
  int tot = s0 + s1 + s2;
  sm[0][t] = tot;
  __syncthreads();
  int cur = 0;
#pragma unroll
  for (int off = 1; off < 512; off <<= 1) {
    int add = (t >= off) ? sm[cur][t - off] : 0;
    sm[cur ^ 1][t] = sm[cur][t] + add;
    __syncthreads();
    cur ^= 1;
  }
  int ex = sm[cur][t] - tot;  // exclusive
  int r0 = p0 + ex, r1 = r0 + s0, r2 = r1 + s1;
  lrs3[3 * t] = r0;
  lrs3[3 * t + 1] = r1;
  lrs3[3 * t + 2] = r2;
  if (t < nnodes) {
    size_t base3 = (size_t)(nodes0 + t) * 3;
    rs3[base3 + 0] = r0;
    rs3[base3 + 1] = r1;
    rs3[base3 + 2] = r2;
  }
  if (b == NB - 1 && t == 0) rs3[(size_t)NN * 3] = NE;
  __syncthreads();
  for (int p = t; p < cnt; p += 512) {
    int pk = (p < CAP) ? stage[p] : binned[p0 + p];
    int key = ((pk >> 19) & 511) * 3 + ((pk >> 17) & 3);
    int off = atomicAdd(&lcur3[key], 1);
    ep[lrs3[key] + off] = pk & 0x1FFFF;  // src only
  }
}

// ---------- per-relation mean aggregation (R10 proven: float4 lane-group
// gather over the unified type-sorted run, position-mask demux) ----------
template <int IN>
__global__ __launch_bounds__(256) void k_agg(
    const float* __restrict__ x, const int* __restrict__ rs3,
    const int* __restrict__ ep, float* __restrict__ h)
{
  constexpr int LPE = IN / 4;            // lanes per edge-row (16 or 8)
  constexpr int DPW = (IN == 32) ? 2 : 1;
  constexpr int SW = 64 / DPW;           // lanes per dst (64 or 32)
  constexpr int EPI = SW / LPE;          // 4 edges per iteration
  int tid = threadIdx.x;
  int wid = (blockIdx.x * 256 + tid) >> 6;
  int lane = tid & 63;
  int sub = lane / SW;
  int sl = lane % SW;
  int k4 = sl % LPE;                     // float4 column within row
  int es = sl / LPE;                     // edge slot 0..3
  int d = wid * DPW + sub;
  if (d >= NN) return;
  int q0 = rs3[3 * d + 0];
  int q1 = rs3[3 * d + 1];
  int q2 = rs3[3 * d + 2];
  int q3 = rs3[3 * d + 3];
  float4 a0 = make_float4(0.f, 0.f, 0.f, 0.f);
  float4 a1 = make_float4(0.f, 0.f, 0.f, 0.f);
  float4 a2 = make_float4(0.f, 0.f, 0.f, 0.f);
#pragma unroll 2
  for (int p = q0; p < q3; p += EPI) {
    int idx = p + es;
    bool val = idx < q3;
    int e = ep[val ? idx : q3 - 1];
    float4 v = *(const float4*)(x + (size_t)e * IN + k4 * 4);
    float m0 = (val && idx < q1) ? 1.f : 0.f;
    float m1 = (val && idx >= q1 && idx < q2) ? 1.f : 0.f;
    float m2 = (val && idx >= q2) ? 1.f : 0.f;
    a0.x = fmaf(m0, v.x, a0.x); a0.y = fmaf(m0, v.y, a0.y);
    a0.z = fmaf(m0, v.z, a0.z); a0.w = fmaf(m0, v.w, a0.w);
    a1.x = fmaf(m1, v.x, a1.x); a1.y = fmaf(m1, v.y, a1.y);
    a1.z = fmaf(m1, v.z, a1.z); a1.w = fmaf(m1, v.w, a1.w);
    a2.x = fmaf(m2, v.x, a2.x); a2.y = fmaf(m2, v.y, a2.y);
    a2.z = fmaf(m2, v.z, a2.z); a2.w = fmaf(m2, v.w, a2.w);
  }
#pragma unroll
  for (int off = LPE; off < SW; off <<= 1) {
    a0.x += __shfl_xor(a0.x, off, 64); a0.y += __shfl_xor(a0.y, off, 64);
    a0.z += __shfl_xor(a0.z, off, 64); a0.w += __shfl_xor(a0.w, off, 64);
    a1.x += __shfl_xor(a1.x, off, 64); a1.y += __shfl_xor(a1.y, off, 64);
    a1.z += __shfl_xor(a1.z, off, 64); a1.w += __shfl_xor(a1.w, off, 64);
    a2.x += __shfl_xor(a2.x, off, 64); a2.y += __shfl_xor(a2.y, off, 64);
    a2.z += __shfl_xor(a2.z, off, 64); a2.w += __shfl_xor(a2.w, off, 64);
  }
  if (es == 0) {
    float* hd = h + (size_t)d * 3 * IN;
    float c0 = (float)(q1 - q0 > 0 ? q1 - q0 : 1);
    float c1 = (float)(q2 - q1 > 0 ? q2 - q1 : 1);
    float c2 = (float)(q3 - q2 > 0 ? q3 - q2 : 1);
    float4 o;
    o.x = a0.x / c0; o.y = a0.y / c0; o.z = a0.z / c0; o.w = a0.w / c0;
    *(float4*)(hd + 0 * IN + k4 * 4) = o;
    o.x = a1.x / c1; o.y = a1.y / c1; o.z = a1.z / c1; o.w = a1.w / c1;
    *(float4*)(hd + 1 * IN + k4 * 4) = o;
    o.x = a2.x / c2; o.y = a2.y / c2; o.z = a2.z / c2; o.w = a2.w / c2;
    *(float4*)(hd + 2 * IN + k4 * 4) = o;
  }
}

// ---------- dense: y[d] = relu(x[d]@root + bias + sum_r h[d][r]@rel_r) ----------
// Stream-pipelined double buffer. R10 staged all 64KB then computed with
// memory idle (duty-cycle bound: VALU 34%, HBM 1 TB/s). R11's fix spilled
// (NPF=8 float4 live across unrolled FMAs -> VGPR 128, 84MB scratch).
// This version overlaps at STREAM granularity with tiny register payload:
// two ping-pong buffers B[2][IN][65] (33KB IN=64 -> 4 blocks/CU = 32
// waves/CU); per stream s: issue s+1's loads to regs (NPF<=2 float4 =
// 8 VGPR), mm(W_s) on B[s&1] (512 FMA hides the latency), barrier,
// commit regs->B[(s+1)&1], barrier. The buffer written at s was last read
// at mm(s-1), two barriers back -> race-free. Non-persistent grid (1563).
// 65-pad keeps write 2-way / read conflict-free (measured-benign).
template <int IN>
__global__ __launch_bounds__(512) void k_mat(
    const float* __restrict__ x, const float* __restrict__ h,
    const float* __restrict__ root, const float* __restrict__ rel,
    const float* __restrict__ bias, float* __restrict__ y)
{
  constexpr int F4 = IN / 4;            // float4 per node-row
  constexpr int NPF = (64 * F4) / 512;  // staged float4 per thread (2 or 1)
  __shared__ float B[2][IN][65];

  const int tid = threadIdx.x;
  const int node0 = blockIdx.x * 64;
  const int n = tid & 63;
  const int j0 = __builtin_amdgcn_readfirstlane((tid >> 6) * 8);

  float4 p[NPF];
  // decode staging slot once: thread covers (nn, c4) pairs
  int s_nn[NPF], s_c4[NPF];
#pragma unroll
  for (int u = 0; u < NPF; ++u) {
    int idx = u * 512 + tid;
    s_nn[u] = idx / F4;
    s_c4[u] = idx % F4;
  }

  auto issue = [&](int s) {  // stream s: 0 = x, 1..3 = h r=s-1
#pragma unroll
    for (int u = 0; u < NPF; ++u) {
      int node = node0 + s_nn[u];
      float4 v = make_float4(0.f, 0.f, 0.f, 0.f);
      if (node < NN) {
        const float* src = (s == 0) ? x + (size_t)node * IN
                                    : h + ((size_t)node * 3 + (s - 1)) * IN;
        v = *(const float4*)(src + s_c4[u] * 4);
      }
      p[u] = v;
    }
  };

  auto commit = [&](int buf) {
#pragma unroll
    for (int u = 0; u < NPF; ++u) {
      int r0 = s_c4[u] * 4, nn = s_nn[u];
      B[buf][r0 + 0][nn] = p[u].x;
      B[buf][r0 + 1][nn] = p[u].y;
      B[buf][r0 + 2][nn] = p[u].z;
      B[buf][r0 + 3][nn] = p[u].w;
    }
  };

  float acc[8];
#pragma unroll
  for (int j = 0; j < 8; ++j) acc[j] = bias[j0 + j];

  auto mm = [&](const float* __restrict__ W, int buf) {
#pragma unroll 4
    for (int k = 0; k < IN; ++k) {
      float sk = B[buf][k][n];
      const float* w = W + (size_t)k * 64 + j0;
#pragma unroll
      for (int j = 0; j < 8; ++j) acc[j] = fmaf(sk, w[j], acc[j]);
    }
  };

  // prologue: stage x -> B0
  issue(0);
  commit(0);
  __syncthreads();

  const float* W[4] = {root, rel, rel + (size_t)IN * 64,
                       rel + (size_t)2 * IN * 64};
#pragma unroll
  for (int s = 0; s < 4; ++s) {
    if (s < 3) issue(s + 1);          // loads in flight under mm below
    mm(W[s], s & 1);
    if (s < 3) {
      __syncthreads();                // all waves done reading B[(s+1)&1]
      commit((s + 1) & 1);            // vmcnt wait + ds_write
      __syncthreads();
    }
  }

  int node = node0 + n;
  if (node < NN) {
    float4* o = (float4*)(y + (size_t)node * 64 + j0);
    float4 v;
    v.x = fmaxf(acc[0], 0.f); v.y = fmaxf(acc[1], 0.f);
    v.z = fmaxf(acc[2], 0.f); v.w = fmaxf(acc[3], 0.f);
    o[0] = v;
    v.x = fmaxf(acc[4], 0.f); v.y = fmaxf(acc[5], 0.f);
    v.z = fmaxf(acc[6], 0.f); v.w = fmaxf(acc[7], 0.f);
    o[1] = v;
  }
}

// ---------- mean pool over sorted batch ids (run-length reduce, then atomic) ----------
__global__ __launch_bounds__(256) void k_pool(
    const float* __restrict__ x3, const int* __restrict__ batch,
    float* __restrict__ pooled, float* __restrict__ gcnt)
{
  int gwave = (blockIdx.x * 256 + threadIdx.x) >> 6;
  int lane = threadIdx.x & 63;
  int n0 = gwave * 64;
  if (n0 >= NN) return;
  int n1 = n0 + 64 < NN ? n0 + 64 : NN;
  int gcur = batch[n0];
  float acc = 0.f;
  int run = 0;
  for (int n = n0; n < n1; ++n) {
    int g = batch[n];
    if (g != gcur) {
      atomicAdd(&pooled[gcur * 64 + lane], acc);
      if (lane == 0) atomicAdd(&gcnt[gcur], (float)run);
      acc = 0.f; run = 0; gcur = g;
    }
    acc += x3[(size_t)n * 64 + lane];
    ++run;
  }
  atomicAdd(&pooled[gcur * 64 + lane], acc);
  if (lane == 0) atomicAdd(&gcnt[gcur], (float)run);
}

// ---------- classifier ----------
__global__ __launch_bounds__(256) void k_cls(
    const float* __restrict__ pooled, const float* __restrict__ gcnt,
    const float* __restrict__ cw, const float* __restrict__ cb, float* __restrict__ out)
{
  int t = blockIdx.x * 256 + threadIdx.x;
  if (t >= NG * 10) return;
  int g = t / 10, c = t % 10;
  float cf = fmaxf(gcnt[g], 1.f);
  float acc = cb[c];
#pragma unroll 8
  for (int k = 0; k < 64; ++k)
    acc += (pooled[g * 64 + k] / cf) * cw[k * 10 + c];
  out[t] = acc;
}

extern "C" void kernel_launch(void* const* d_in, const int* in_sizes, int n_in,
                              void* d_out, int out_size, void* d_ws, size_t ws_size,
                              hipStream_t stream)
{
  const int* nf = (const int*)d_in[0];
  const int* ei = (const int*)d_in[1];
  const int* et = (const int*)d_in[2];
  const int* batch = (const int*)d_in[3];
  const float* semb = (const float*)d_in[4];
  const float* cemb = (const float*)d_in[5];
  const float* pw = (const float*)d_in[6];
  const float* pb = (const float*)d_in[7];
  const float* root1 = (const float*)d_in[8];
  const float* rel1 = (const float*)d_in[9];
  const float* bias1 = (const float*)d_in[10];
  const float* root2 = (const float*)d_in[11];
  const float* rel2 = (const float*)d_in[12];
  const float* bias2 = (const float*)d_in[13];
  const float* cw = (const float*)d_in[14];
  const float* cb = (const float*)d_in[15];
  float* out = (float*)d_out;

  char* ws = (char*)d_ws;
  size_t off = 0;
  auto alloc = [&](size_t bytes) {
    char* p = ws + off;
    off += (bytes + 255) & ~(size_t)255;
    return p;
  };
  int* bkt_cnt = (int*)alloc((size_t)NB * 4);
  int* bkt_base = (int*)alloc((size_t)(NB + 1) * 4);
  int* bkt_cur = (int*)alloc((size_t)NB * 4);
  int* rs3 = (int*)alloc(((size_t)NN * 3 + 1) * 4);  // per-(node,type) run starts
  int* ep = (int*)alloc((size_t)NE * 4 + 256);       // src, type-sorted CSR order
  float* xA = (float*)alloc((size_t)NN * 64 * 4);    // x2
  float* xB = (float*)alloc((size_t)NN * 64 * 4);    // x1 ([N,32]) then x3
  float* h = (float*)alloc((size_t)3 * NN * 64 * 4); // h[d][r][IN]
  float* pooled = (float*)alloc((size_t)NG * 64 * 4);
  float* gcnt = (float*)alloc((size_t)NG * 4);
  int* binned = (int*)h;  // phase-A output; consumed by kB_build before k_agg writes h
  (void)ws_size; (void)in_sizes; (void)n_in; (void)out_size;

  hipMemsetAsync(bkt_cnt, 0, (size_t)NB * 4, stream);
  k_embed<<<(NN + 255) / 256, 256, 0, stream>>>(nf, semb, cemb, pw, pb, xB);

  // CSR build: bucketed counting sort, type-sorted within node
  kA_count<<<NAB, 256, 0, stream>>>(ei, bkt_cnt);
  kA_scan<<<1, 256, 0, stream>>>(bkt_cnt, bkt_base, bkt_cur);
  kA_scatter<<<NAB, 256, 0, stream>>>(ei, et, bkt_cur, binned);
  kB_build<<<NB, 512, 0, stream>>>(bkt_base, binned, rs3, ep);

  int matgrid = (NN + 63) / 64;  // 1563 blocks, 64 nodes each

  // layer 1: x1[N,32] (xB) -> h -> x2[N,64] (xA)
  k_agg<32><<<(NN / 2 + 3) / 4 + 1, 256, 0, stream>>>(xB, rs3, ep, h);
  k_mat<32><<<matgrid, 512, 0, stream>>>(xB, h, root1, rel1, bias1, xA);
  // layer 2: x2 (xA) -> h -> x3 (xB)
  k_agg<64><<<(NN + 3) / 4, 256, 0, stream>>>(xA, rs3, ep, h);
  k_mat<64><<<matgrid, 512, 0, stream>>>(xA, h, root2, rel2, bias2, xB);

  hipMemsetAsync(pooled, 0, (size_t)NG * 64 * 4, stream);
  hipMemsetAsync(gcnt, 0, (size_t)NG * 4, stream);
  int nwaves = (NN + 63) / 64;
  k_pool<<<(nwaves + 3) / 4, 256, 0, stream>>>(xB, batch, pooled, gcnt);
  k_cls<<<(NG * 10 + 255) / 256, 256, 0, stream>>>(pooled, gcnt, cw, cb, out);
}

// Round 13
// 289.002 us; speedup vs baseline: 4.9558x; 1.0183x over previous
//
#include <hip/hip_runtime.h>

#define NN 100000
#define NE 1600000
#define NG 512

#define BSH 9                         // bucket = dst >> 9 (512 nodes/bucket)
#define NB 196                        // ceil(NN / 512)
#define EPB 8192                      // edges per block in phase A
#define NAB ((NE + EPB - 1) / EPB)    // 196 phase-A blocks
#define CAP 9216                      // LDS staging capacity in kB_build

// ---------- embedding lookup + pre-linear + relu: x1[N,32] ----------
__global__ __launch_bounds__(256) void k_embed(
    const int* __restrict__ nf, const float* __restrict__ semb,
    const float* __restrict__ cemb, const float* __restrict__ pw,
    const float* __restrict__ pb, float* __restrict__ x1)
{
  int gid = blockIdx.x * 256 + threadIdx.x;
  bool valid = gid < NN;
  int i = valid ? gid : NN - 1;
  int sf = nf[2 * i], cf = nf[2 * i + 1];
  float x0[16];
#pragma unroll
  for (int k = 0; k < 8; ++k) x0[k] = semb[sf * 8 + k];
#pragma unroll
  for (int k = 0; k < 8; ++k) x0[8 + k] = cemb[cf * 8 + k];
  float acc[32];
#pragma unroll
  for (int j = 0; j < 32; ++j) acc[j] = pb[j];
#pragma unroll
  for (int k = 0; k < 16; ++k) {
    float xv = x0[k];
#pragma unroll
    for (int j = 0; j < 32; ++j) acc[j] += xv * pw[k * 32 + j];
  }
  if (valid) {
    float4* o = (float4*)(x1 + (size_t)i * 32);
#pragma unroll
    for (int j4 = 0; j4 < 8; ++j4) {
      float4 v;
      v.x = fmaxf(acc[4 * j4 + 0], 0.f);
      v.y = fmaxf(acc[4 * j4 + 1], 0.f);
      v.z = fmaxf(acc[4 * j4 + 2], 0.f);
      v.w = fmaxf(acc[4 * j4 + 3], 0.f);
      o[j4] = v;
    }
  }
}

// ---------- CSR build via bucketed counting sort ----------

__global__ __launch_bounds__(256) void kA_count(
    const int* __restrict__ ei, int* __restrict__ bkt_cnt)
{
  __shared__ int lh[NB];
  for (int b = threadIdx.x; b < NB; b += 256) lh[b] = 0;
  __syncthreads();
  int base = blockIdx.x * EPB;
#pragma unroll
  for (int i = 0; i < EPB / 256; ++i) {
    int e = base + i * 256 + threadIdx.x;
    if (e < NE) atomicAdd(&lh[ei[NE + e] >> BSH], 1);
  }
  __syncthreads();
  for (int b = threadIdx.x; b < NB; b += 256)
    if (lh[b]) atomicAdd(&bkt_cnt[b], lh[b]);
}

__global__ __launch_bounds__(256) void kA_scan(
    const int* __restrict__ bkt_cnt, int* __restrict__ bkt_base,
    int* __restrict__ bkt_cur)
{
  __shared__ int sm[2][256];
  int t = threadIdx.x;
  int v = (t < NB) ? bkt_cnt[t] : 0;
  sm[0][t] = v;
  __syncthreads();
  int cur = 0;
#pragma unroll
  for (int off = 1; off < 256; off <<= 1) {
    int add = (t >= off) ? sm[cur][t - off] : 0;
    sm[cur ^ 1][t] = sm[cur][t] + add;
    __syncthreads();
    cur ^= 1;
  }
  if (t < NB) {
    int ex = sm[cur][t] - v;
    bkt_base[t] = ex;
    bkt_cur[t] = ex;
  }
  if (t == 0) bkt_base[NB] = NE;
}

// pack: src(0-16) | type(17-18) | dst&511 (19-27)
__global__ __launch_bounds__(256) void kA_scatter(
    const int* __restrict__ ei, const int* __restrict__ et,
    int* __restrict__ bkt_cur, int* __restrict__ binned)
{
  __shared__ int packA[EPB];
  __shared__ unsigned char bktA[EPB];
  __shared__ int lh[NB], grun[NB], lcur[NB];
  for (int b = threadIdx.x; b < NB; b += 256) { lh[b] = 0; lcur[b] = 0; }
  __syncthreads();
  int base = blockIdx.x * EPB;
#pragma unroll
  for (int i = 0; i < EPB / 256; ++i) {
    int p = i * 256 + threadIdx.x;
    int e = base + p;
    if (e < NE) {
      int src = ei[e], dst = ei[NE + e], ty = et[e];
      int b = dst >> BSH;
      packA[p] = src | (ty << 17) | ((dst & 511) << 19);
      bktA[p] = (unsigned char)b;
      atomicAdd(&lh[b], 1);
    } else {
      bktA[p] = 255;
    }
  }
  __syncthreads();
  for (int b = threadIdx.x; b < NB; b += 256)
    grun[b] = lh[b] ? atomicAdd(&bkt_cur[b], lh[b]) : 0;
  __syncthreads();
#pragma unroll
  for (int i = 0; i < EPB / 256; ++i) {
    int p = i * 256 + threadIdx.x;
    int b = bktA[p];
    if (b != 255) {
      int off = atomicAdd(&lcur[b], 1);
      binned[grun[b] + off] = packA[p];
    }
  }
}

// Phase B: one workgroup per bucket; key = dst_local*3 + type -> per-node
// edge list sorted by relation; rs3[d*3+r] run boundaries; ep stores src.
__global__ __launch_bounds__(512) void kB_build(
    const int* __restrict__ bkt_base, const int* __restrict__ binned,
    int* __restrict__ rs3, int* __restrict__ ep)
{
  __shared__ int stage[CAP];
  __shared__ int ldeg3[1536], lrs3[1536], lcur3[1536];
  __shared__ int sm[2][512];
  int b = blockIdx.x;
  int t = threadIdx.x;
  int p0 = bkt_base[b], p1 = bkt_base[b + 1];
  int cnt = p1 - p0;
  int nodes0 = b << BSH;
  int nnodes = NN - nodes0 < 512 ? NN - nodes0 : 512;
  ldeg3[t] = 0; ldeg3[t + 512] = 0; ldeg3[t + 1024] = 0;
  lcur3[t] = 0; lcur3[t + 512] = 0; lcur3[t + 1024] = 0;
  __syncthreads();
  for (int p = t; p < cnt; p += 512) {
    int pk = binned[p0 + p];
    if (p < CAP) stage[p] = pk;
    int key = ((pk >> 19) & 511) * 3 + ((pk >> 17) & 3);
    atomicAdd(&ldeg3[key], 1);
  }
  __syncthreads();
  int s0 = ldeg3[3 * t], s1 = ldeg3[3 * t + 1], s2 = ldeg3[3 * t + 2];
  int tot = s0 + s1 + s2;
  sm[0][t] = tot;
  __syncthreads();
  int cur = 0;
#pragma unroll
  for (int off = 1; off < 512; off <<= 1) {
    int add = (t >= off) ? sm[cur][t - off] : 0;
    sm[cur ^ 1][t] = sm[cur][t] + add;
    __syncthreads();
    cur ^= 1;
  }
  int ex = sm[cur][t] - tot;  // exclusive
  int r0 = p0 + ex, r1 = r0 + s0, r2 = r1 + s1;
  lrs3[3 * t] = r0;
  lrs3[3 * t + 1] = r1;
  lrs3[3 * t + 2] = r2;
  if (t < nnodes) {
    size_t base3 = (size_t)(nodes0 + t) * 3;
    rs3[base3 + 0] = r0;
    rs3[base3 + 1] = r1;
    rs3[base3 + 2] = r2;
  }
  if (b == NB - 1 && t == 0) rs3[(size_t)NN * 3] = NE;
  __syncthreads();
  for (int p = t; p < cnt; p += 512) {
    int pk = (p < CAP) ? stage[p] : binned[p0 + p];
    int key = ((pk >> 19) & 511) * 3 + ((pk >> 17) & 3);
    int off = atomicAdd(&lcur3[key], 1);
    ep[lrs3[key] + off] = pk & 0x1FFFF;  // src only
  }
}

// ---------- FUSED agg + dense: y[d] = relu(x[d]@root + b + sum_r mean_r@rel_r) ----
// R8's fusion retried with the R10/R12-PROVEN gather shape (R8 failed only
// because its phase A was the per-feature-lane latency-bound gather).
// Block = 512 thr owns 64 dsts. Phase A: each wave runs the verbatim R10
// loop (float4 lane-group: LPE lanes read one row as float4, 4 edges/iter
// in flight; unified run [q0,q3) so the pipeline fills; position-mask
// demux) for 8 dsts serially, then writes the means DIRECTLY into the
// transposed LDS tile smem[r*IN+k][dl] -- the h[N,3,IN] HBM round-trip
// (75+38 MB write + refetch) never exists. d>=NN yields zeros naturally
// (q's=0). Write: 16 lanes, stride-260 floats -> 2-way bank (free).
// Phase B: R8's dense tail: 3 rel-mm's from LDS (read smem[row][n],
// stride-1, conflict-free), x prefetched to regs (NPF<=2 float4 -- no
// R11 spill), restaged over mean0's rows, root-mm. Weights via s_load
// (j0 readfirstlane). LDS 3*IN x 65 = 49.9KB (IN=64) -> 3 blocks/CU;
// phase A of one block overlaps phase B of neighbors.
template <int IN>
__global__ __launch_bounds__(512) void k_fused(
    const float* __restrict__ x, const int* __restrict__ rs3,
    const int* __restrict__ ep, const float* __restrict__ root,
    const float* __restrict__ rel, const float* __restrict__ bias,
    float* __restrict__ y)
{
  __shared__ float smem[3 * IN][65];
  const int tid = threadIdx.x;
  const int node0 = blockIdx.x * 64;
  const int wv = tid >> 6;
  const int lane = tid & 63;

  constexpr int LPE = IN / 4;              // lanes per edge-row (16 or 8)
  constexpr int DPW = (IN == 32) ? 2 : 1;  // dsts per wave-iteration
  constexpr int SW = 64 / DPW;             // lanes per dst (64 or 32)
  constexpr int EPI = SW / LPE;            // 4 edges per iteration
  const int sub = (IN == 64) ? 0 : (lane >> 5);
  const int sl = lane % SW;
  const int k4 = sl % LPE;                 // float4 column within row
  const int es = sl / LPE;                 // edge slot 0..3

  // ================= Phase A: gather means into transposed LDS ==============
  for (int it = 0; it < 8 / DPW; ++it) {
    int dl = wv * 8 + it * DPW + sub;      // local dst 0..63 (exclusive per wave)
    int d = node0 + dl;
    int q0 = 0, q1 = 0, q2 = 0, q3 = 0;
    if (d < NN) {
      q0 = rs3[3 * d + 0];
      q1 = rs3[3 * d + 1];
      q2 = rs3[3 * d + 2];
      q3 = rs3[3 * d + 3];
    }
    float4 a0 = make_float4(0.f, 0.f, 0.f, 0.f);
    float4 a1 = make_float4(0.f, 0.f, 0.f, 0.f);
    float4 a2 = make_float4(0.f, 0.f, 0.f, 0.f);
#pragma unroll 2
    for (int p = q0; p < q3; p += EPI) {
      int idx = p + es;
      bool val = idx < q3;
      int e = ep[val ? idx : q3 - 1];
      float4 v = *(const float4*)(x + (size_t)e * IN + k4 * 4);
      float m0 = (val && idx < q1) ? 1.f : 0.f;
      float m1 = (val && idx >= q1 && idx < q2) ? 1.f : 0.f;
      float m2 = (val && idx >= q2) ? 1.f : 0.f;
      a0.x = fmaf(m0, v.x, a0.x); a0.y = fmaf(m0, v.y, a0.y);
      a0.z = fmaf(m0, v.z, a0.z); a0.w = fmaf(m0, v.w, a0.w);
      a1.x = fmaf(m1, v.x, a1.x); a1.y = fmaf(m1, v.y, a1.y);
      a1.z = fmaf(m1, v.z, a1.z); a1.w = fmaf(m1, v.w, a1.w);
      a2.x = fmaf(m2, v.x, a2.x); a2.y = fmaf(m2, v.y, a2.y);
      a2.z = fmaf(m2, v.z, a2.z); a2.w = fmaf(m2, v.w, a2.w);
    }
#pragma unroll
    for (int off = LPE; off < SW; off <<= 1) {
      a0.x += __shfl_xor(a0.x, off, 64); a0.y += __shfl_xor(a0.y, off, 64);
      a0.z += __shfl_xor(a0.z, off, 64); a0.w += __shfl_xor(a0.w, off, 64);
      a1.x += __shfl_xor(a1.x, off, 64); a1.y += __shfl_xor(a1.y, off, 64);
      a1.z += __shfl_xor(a1.z, off, 64); a1.w += __shfl_xor(a1.w, off, 64);
      a2.x += __shfl_xor(a2.x, off, 64); a2.y += __shfl_xor(a2.y, off, 64);
      a2.z += __shfl_xor(a2.z, off, 64); a2.w += __shfl_xor(a2.w, off, 64);
    }
    if (es == 0) {
      float c0 = (float)(q1 - q0 > 0 ? q1 - q0 : 1);
      float c1 = (float)(q2 - q1 > 0 ? q2 - q1 : 1);
      float c2 = (float)(q3 - q2 > 0 ? q3 - q2 : 1);
      int r0 = k4 * 4;
      smem[0 * IN + r0 + 0][dl] = a0.x / c0;
      smem[0 * IN + r0 + 1][dl] = a0.y / c0;
      smem[0 * IN + r0 + 2][dl] = a0.z / c0;
      smem[0 * IN + r0 + 3][dl] = a0.w / c0;
      smem[1 * IN + r0 + 0][dl] = a1.x / c1;
      smem[1 * IN + r0 + 1][dl] = a1.y / c1;
      smem[1 * IN + r0 + 2][dl] = a1.z / c1;
      smem[1 * IN + r0 + 3][dl] = a1.w / c1;
      smem[2 * IN + r0 + 0][dl] = a2.x / c2;
      smem[2 * IN + r0 + 1][dl] = a2.y / c2;
      smem[2 * IN + r0 + 2][dl] = a2.z / c2;
      smem[2 * IN + r0 + 3][dl] = a2.w / c2;
    }
  }
  __syncthreads();

  // ================= Phase B: dense =================
  const int n = lane;
  const int j0 = __builtin_amdgcn_readfirstlane(wv * 8);
  constexpr int F4 = IN / 4;
  constexpr int NPF = (64 * F4) / 512;   // x prefetch float4 per thread (2 or 1)

  // issue x prefetch now; latency hides under the three rel matmuls
  float4 pf[NPF];
#pragma unroll
  for (int u = 0; u < NPF; ++u) {
    int idx = u * 512 + tid;
    int nn = idx / F4, c4 = idx % F4;
    int node = node0 + nn;
    pf[u] = make_float4(0.f, 0.f, 0.f, 0.f);
    if (node < NN) pf[u] = *(const float4*)(x + (size_t)node * IN + c4 * 4);
  }

  float acc[8];
#pragma unroll
  for (int j = 0; j < 8; ++j) acc[j] = bias[j0 + j];

  auto mm = [&](const float* __restrict__ W, int row0) {
#pragma unroll 4
    for (int k = 0; k < IN; ++k) {
      float sk = smem[row0 + k][n];
      const float* w = W + (size_t)k * 64 + j0;
#pragma unroll
      for (int j = 0; j < 8; ++j) acc[j] = fmaf(sk, w[j], acc[j]);
    }
  };

  mm(rel, 0);                             // mean0 @ rel0
  mm(rel + (size_t)IN * 64, IN);          // mean1 @ rel1
  mm(rel + (size_t)2 * IN * 64, 2 * IN);  // mean2 @ rel2
  __syncthreads();

  // restage x over rows [0, IN) from registers (mean0 already consumed)
#pragma unroll
  for (int u = 0; u < NPF; ++u) {
    int idx = u * 512 + tid;
    int nn = idx / F4, c4 = idx % F4;
    smem[c4 * 4 + 0][nn] = pf[u].x;
    smem[c4 * 4 + 1][nn] = pf[u].y;
    smem[c4 * 4 + 2][nn] = pf[u].z;
    smem[c4 * 4 + 3][nn] = pf[u].w;
  }
  __syncthreads();
  mm(root, 0);                            // x @ root

  int node = node0 + n;
  if (node < NN) {
    float4* o = (float4*)(y + (size_t)node * 64 + j0);
    float4 v;
    v.x = fmaxf(acc[0], 0.f); v.y = fmaxf(acc[1], 0.f);
    v.z = fmaxf(acc[2], 0.f); v.w = fmaxf(acc[3], 0.f);
    o[0] = v;
    v.x = fmaxf(acc[4], 0.f); v.y = fmaxf(acc[5], 0.f);
    v.z = fmaxf(acc[6], 0.f); v.w = fmaxf(acc[7], 0.f);
    o[1] = v;
  }
}

// ---------- mean pool over sorted batch ids (run-length reduce, then atomic) ----------
__global__ __launch_bounds__(256) void k_pool(
    const float* __restrict__ x3, const int* __restrict__ batch,
    float* __restrict__ pooled, float* __restrict__ gcnt)
{
  int gwave = (blockIdx.x * 256 + threadIdx.x) >> 6;
  int lane = threadIdx.x & 63;
  int n0 = gwave * 64;
  if (n0 >= NN) return;
  int n1 = n0 + 64 < NN ? n0 + 64 : NN;
  int gcur = batch[n0];
  float acc = 0.f;
  int run = 0;
  for (int n = n0; n < n1; ++n) {
    int g = batch[n];
    if (g != gcur) {
      atomicAdd(&pooled[gcur * 64 + lane], acc);
      if (lane == 0) atomicAdd(&gcnt[gcur], (float)run);
      acc = 0.f; run = 0; gcur = g;
    }
    acc += x3[(size_t)n * 64 + lane];
    ++run;
  }
  atomicAdd(&pooled[gcur * 64 + lane], acc);
  if (lane == 0) atomicAdd(&gcnt[gcur], (float)run);
}

// ---------- classifier ----------
__global__ __launch_bounds__(256) void k_cls(
    const float* __restrict__ pooled, const float* __restrict__ gcnt,
    const float* __restrict__ cw, const float* __restrict__ cb, float* __restrict__ out)
{
  int t = blockIdx.x * 256 + threadIdx.x;
  if (t >= NG * 10) return;
  int g = t / 10, c = t % 10;
  float cf = fmaxf(gcnt[g], 1.f);
  float acc = cb[c];
#pragma unroll 8
  for (int k = 0; k < 64; ++k)
    acc += (pooled[g * 64 + k] / cf) * cw[k * 10 + c];
  out[t] = acc;
}

extern "C" void kernel_launch(void* const* d_in, const int* in_sizes, int n_in,
                              void* d_out, int out_size, void* d_ws, size_t ws_size,
                              hipStream_t stream)
{
  const int* nf = (const int*)d_in[0];
  const int* ei = (const int*)d_in[1];
  const int* et = (const int*)d_in[2];
  const int* batch = (const int*)d_in[3];
  const float* semb = (const float*)d_in[4];
  const float* cemb = (const float*)d_in[5];
  const float* pw = (const float*)d_in[6];
  const float* pb = (const float*)d_in[7];
  const float* root1 = (const float*)d_in[8];
  const float* rel1 = (const float*)d_in[9];
  const float* bias1 = (const float*)d_in[10];
  const float* root2 = (const float*)d_in[11];
  const float* rel2 = (const float*)d_in[12];
  const float* bias2 = (const float*)d_in[13];
  const float* cw = (const float*)d_in[14];
  const float* cb = (const float*)d_in[15];
  float* out = (float*)d_out;

  char* ws = (char*)d_ws;
  size_t off = 0;
  auto alloc = [&](size_t bytes) {
    char* p = ws + off;
    off += (bytes + 255) & ~(size_t)255;
    return p;
  };
  int* bkt_cnt = (int*)alloc((size_t)NB * 4);
  int* bkt_base = (int*)alloc((size_t)(NB + 1) * 4);
  int* bkt_cur = (int*)alloc((size_t)NB * 4);
  int* rs3 = (int*)alloc(((size_t)NN * 3 + 1) * 4);  // per-(node,type) run starts
  int* ep = (int*)alloc((size_t)NE * 4 + 256);       // src, type-sorted CSR order
  int* binned = (int*)alloc((size_t)NE * 4);         // phase-A binning buffer
  float* xA = (float*)alloc((size_t)NN * 64 * 4);    // x2
  float* xB = (float*)alloc((size_t)NN * 64 * 4);    // x1 ([N,32]) then x3
  float* pooled = (float*)alloc((size_t)NG * 64 * 4);
  float* gcnt = (float*)alloc((size_t)NG * 4);
  (void)ws_size; (void)in_sizes; (void)n_in; (void)out_size;

  hipMemsetAsync(bkt_cnt, 0, (size_t)NB * 4, stream);
  k_embed<<<(NN + 255) / 256, 256, 0, stream>>>(nf, semb, cemb, pw, pb, xB);

  // CSR build: bucketed counting sort, type-sorted within node
  kA_count<<<NAB, 256, 0, stream>>>(ei, bkt_cnt);
  kA_scan<<<1, 256, 0, stream>>>(bkt_cnt, bkt_base, bkt_cur);
  kA_scatter<<<NAB, 256, 0, stream>>>(ei, et, bkt_cur, binned);
  kB_build<<<NB, 512, 0, stream>>>(bkt_base, binned, rs3, ep);

  int fgrid = (NN + 63) / 64;  // 1563 blocks, 64 dsts each

  // layer 1: x1 (xB) -> x2 (xA);  layer 2: x2 (xA) -> x3 (xB)
  k_fused<32><<<fgrid, 512, 0, stream>>>(xB, rs3, ep, root1, rel1, bias1, xA);
  k_fused<64><<<fgrid, 512, 0, stream>>>(xA, rs3, ep, root2, rel2, bias2, xB);

  hipMemsetAsync(pooled, 0, (size_t)NG * 64 * 4, stream);
  hipMemsetAsync(gcnt, 0, (size_t)NG * 4, stream);
  int nwaves = (NN + 63) / 64;
  k_pool<<<(nwaves + 3) / 4, 256, 0, stream>>>(xB, batch, pooled, gcnt);
  k_cls<<<(NG * 10 + 255) / 256, 256, 0, stream>>>(pooled, gcnt, cw, cb, out);
}